// Round 1
// baseline (774.536 us; speedup 1.0000x reference)
//
#include <hip/hip_runtime.h>

#define NUM_USERS 60000
#define NUM_ITEMS 30000
#define N_NODES   90000
#define EDIM      64
#define NEDGES    1000000

// ---------------------------------------------------------------- degree
__global__ void deg_kernel(const int* __restrict__ ei, int* __restrict__ deg, int E) {
    int i = blockIdx.x * blockDim.x + threadIdx.x;
    if (i >= E) return;
    int r = ei[i];        // user node id
    int c = ei[E + i];    // item node id (already offset by NUM_USERS)
    atomicAdd(&deg[r], 1);
    atomicAdd(&deg[c], 1);
}

// ---------------------------------------------------------------- dinv
__global__ void dinv_kernel(const int* __restrict__ deg, float* __restrict__ dinv, int n) {
    int v = blockIdx.x * blockDim.x + threadIdx.x;
    if (v >= n) return;
    int d = deg[v];
    dinv[v] = (d > 0) ? (1.0f / sqrtf((float)d)) : 0.0f;
}

// ---------------------------------------------------------------- exclusive scan (single block)
__global__ void scan_kernel(const int* __restrict__ deg, int* __restrict__ row_ptr,
                            int* __restrict__ cursor, int n) {
    __shared__ int sdata[1024];
    int tid = threadIdx.x;
    int carry = 0;
    for (int base = 0; base < n; base += 1024) {
        int i = base + tid;
        int v = (i < n) ? deg[i] : 0;
        sdata[tid] = v;
        __syncthreads();
        for (int offset = 1; offset < 1024; offset <<= 1) {
            int t = (tid >= offset) ? sdata[tid - offset] : 0;
            __syncthreads();
            sdata[tid] += t;
            __syncthreads();
        }
        int incl = sdata[tid];
        if (i < n) {
            int excl = carry + incl - v;
            row_ptr[i] = excl;
            cursor[i]  = excl;
        }
        carry += sdata[1023];
        __syncthreads();
    }
    if (tid == 0) row_ptr[n] = carry;
}

// ---------------------------------------------------------------- CSR fill (counting-sort scatter)
__global__ void fill_kernel(const int* __restrict__ ei, int* __restrict__ cursor,
                            int* __restrict__ csr_src, int E) {
    int i = blockIdx.x * blockDim.x + threadIdx.x;
    if (i >= E) return;
    int r = ei[i];
    int c = ei[E + i];
    int p1 = atomicAdd(&cursor[c], 1);
    csr_src[p1] = r;                 // edge (r -> c): c's bucket gets source r
    int p2 = atomicAdd(&cursor[r], 1);
    csr_src[p2] = c;                 // reversed edge (c -> r)
}

// ---------------------------------------------------------------- init embS0 = dinv*emb0, acc = emb0
__global__ void init_kernel(const float* __restrict__ user_emb,
                            const float* __restrict__ item_emb,
                            const float* __restrict__ dinv,
                            float* __restrict__ embS, float* __restrict__ out) {
    int idx = blockIdx.x * blockDim.x + threadIdx.x;   // over N_NODES*EDIM
    if (idx >= N_NODES * EDIM) return;
    int v = idx >> 6;
    float e = (v < NUM_USERS) ? user_emb[idx] : item_emb[idx - NUM_USERS * EDIM];
    out[idx]  = e;
    embS[idx] = dinv[v] * e;
}

// ---------------------------------------------------------------- one propagation layer (pull)
// wave per node, lane = embedding dim. embS_in[src] gathers are coalesced 256B.
template <int LAST>
__global__ void layer_kernel(const int* __restrict__ row_ptr,
                             const int* __restrict__ csr_src,
                             const float* __restrict__ dinv,
                             const float* __restrict__ embS_in,
                             float* __restrict__ embS_out,
                             float* __restrict__ out) {
    int wid  = (blockIdx.x * blockDim.x + threadIdx.x) >> 6;
    int lane = threadIdx.x & 63;
    if (wid >= N_NODES) return;
    int start = row_ptr[wid];
    int end   = row_ptr[wid + 1];
    float sum = 0.0f;
    for (int j0 = start; j0 < end; j0 += 64) {
        int idx   = j0 + lane;
        int mysrc = (idx < end) ? csr_src[idx] : 0;   // coalesced chunk of sources
        int cnt   = min(64, end - j0);
        for (int t = 0; t < cnt; ++t) {
            int src = __shfl(mysrc, t);               // wave-uniform broadcast
            sum += embS_in[(size_t)src * EDIM + lane];
        }
    }
    float dv = dinv[wid];
    float e  = dv * sum;
    size_t o = (size_t)wid * EDIM + lane;
    if (LAST) {
        out[o] = (out[o] + e) * 0.25f;                // (acc + emb3) / (L+1)
    } else {
        out[o] += e;                                   // acc += emb_l
        embS_out[o] = dv * e;                          // state for next layer
    }
}

// ----------------------------------------------------------------
extern "C" void kernel_launch(void* const* d_in, const int* in_sizes, int n_in,
                              void* d_out, int out_size, void* d_ws, size_t ws_size,
                              hipStream_t stream) {
    const int*   ei       = (const int*)d_in[0];     // [2, E] int32
    const float* user_emb = (const float*)d_in[1];
    const float* item_emb = (const float*)d_in[2];
    float*       out      = (float*)d_out;

    char* ws = (char*)d_ws;
    size_t off = 0;
    auto alloc = [&](size_t bytes) -> void* {
        void* p = ws + off;
        off = (off + bytes + 255) & ~(size_t)255;
        return p;
    };

    int*   deg     = (int*)  alloc((size_t)N_NODES * 4);
    float* dinv    = (float*)alloc((size_t)N_NODES * 4);
    int*   row_ptr = (int*)  alloc(((size_t)N_NODES + 1) * 4);
    int*   cursor  = (int*)  alloc((size_t)N_NODES * 4);
    int*   csr_src = (int*)  alloc((size_t)2 * NEDGES * 4);
    float* embS0   = (float*)alloc((size_t)N_NODES * EDIM * 4);
    float* embS1   = (float*)alloc((size_t)N_NODES * EDIM * 4);

    hipMemsetAsync(deg, 0, (size_t)N_NODES * 4, stream);

    const int B = 256;
    deg_kernel<<<(NEDGES + B - 1) / B, B, 0, stream>>>(ei, deg, NEDGES);
    dinv_kernel<<<(N_NODES + B - 1) / B, B, 0, stream>>>(deg, dinv, N_NODES);
    scan_kernel<<<1, 1024, 0, stream>>>(deg, row_ptr, cursor, N_NODES);
    fill_kernel<<<(NEDGES + B - 1) / B, B, 0, stream>>>(ei, cursor, csr_src, NEDGES);

    int elems = N_NODES * EDIM;
    init_kernel<<<(elems + B - 1) / B, B, 0, stream>>>(user_emb, item_emb, dinv, embS0, out);

    int lgrid = (N_NODES * 64 + B - 1) / B;   // one wave (64 lanes) per node
    layer_kernel<0><<<lgrid, B, 0, stream>>>(row_ptr, csr_src, dinv, embS0, embS1, out);
    layer_kernel<0><<<lgrid, B, 0, stream>>>(row_ptr, csr_src, dinv, embS1, embS0, out);
    layer_kernel<1><<<lgrid, B, 0, stream>>>(row_ptr, csr_src, dinv, embS0, nullptr, out);
}

// Round 2
// 616.777 us; speedup vs baseline: 1.2558x; 1.2558x over previous
//
#include <hip/hip_runtime.h>
#include <hip/hip_bf16.h>

#define NUM_USERS 60000
#define NUM_ITEMS 30000
#define N_NODES   90000
#define EDIM      64
#define NEDGES    1000000
#define SCAN_B    1024
#define SCAN_NB   ((N_NODES + SCAN_B - 1) / SCAN_B)   // 88

// ---------------------------------------------------------------- degree
__global__ void deg_kernel(const int* __restrict__ ei, int* __restrict__ deg, int E) {
    int i = blockIdx.x * blockDim.x + threadIdx.x;
    if (i >= E) return;
    int r = ei[i];        // user node id
    int c = ei[E + i];    // item node id (already offset by NUM_USERS)
    atomicAdd(&deg[r], 1);
    atomicAdd(&deg[c], 1);
}

// ---------------------------------------------------------------- dinv
__global__ void dinv_kernel(const int* __restrict__ deg, float* __restrict__ dinv, int n) {
    int v = blockIdx.x * blockDim.x + threadIdx.x;
    if (v >= n) return;
    int d = deg[v];
    dinv[v] = (d > 0) ? (1.0f / sqrtf((float)d)) : 0.0f;
}

// ---------------------------------------------------------------- parallel scan, stage 1:
// per-block local exclusive scan + block totals
__global__ void scan_block(const int* __restrict__ deg, int* __restrict__ lexcl,
                           int* __restrict__ bsum, int n) {
    __shared__ int sdata[SCAN_B];
    int tid = threadIdx.x;
    int i = blockIdx.x * SCAN_B + tid;
    int v = (i < n) ? deg[i] : 0;
    sdata[tid] = v;
    __syncthreads();
    for (int offset = 1; offset < SCAN_B; offset <<= 1) {
        int t = (tid >= offset) ? sdata[tid - offset] : 0;
        __syncthreads();
        sdata[tid] += t;
        __syncthreads();
    }
    if (i < n) lexcl[i] = sdata[tid] - v;
    if (tid == SCAN_B - 1) bsum[blockIdx.x] = sdata[tid];
}

// ---------------------------------------------------------------- stage 2: exclusive scan of 88 partials
__global__ void scan_partials(int* __restrict__ bsum, int nb) {
    if (threadIdx.x == 0) {
        int run = 0;
        for (int b = 0; b < nb; ++b) {
            int v = bsum[b];
            bsum[b] = run;
            run += v;
        }
    }
}

// ---------------------------------------------------------------- stage 3: add block offsets
__global__ void scan_add(const int* __restrict__ lexcl, const int* __restrict__ bsum,
                         int* __restrict__ row_ptr, int* __restrict__ cursor, int n) {
    int i = blockIdx.x * blockDim.x + threadIdx.x;
    if (i >= n) return;
    int val = lexcl[i] + bsum[i >> 10];
    row_ptr[i] = val;
    cursor[i]  = val;
    if (i == 0) row_ptr[n] = 2 * NEDGES;
}

// ---------------------------------------------------------------- CSR fill (counting-sort scatter)
__global__ void fill_kernel(const int* __restrict__ ei, int* __restrict__ cursor,
                            int* __restrict__ csr_src, int E) {
    int i = blockIdx.x * blockDim.x + threadIdx.x;
    if (i >= E) return;
    int r = ei[i];
    int c = ei[E + i];
    int p1 = atomicAdd(&cursor[c], 1);
    csr_src[p1] = r;                 // edge (r -> c): c's bucket gets source r
    int p2 = atomicAdd(&cursor[r], 1);
    csr_src[p2] = c;                 // reversed edge (c -> r)
}

// ---------------------------------------------------------------- init embS0 = bf16(dinv*emb0), acc = emb0
__global__ void init_kernel(const float* __restrict__ user_emb,
                            const float* __restrict__ item_emb,
                            const float* __restrict__ dinv,
                            __hip_bfloat16* __restrict__ embS, float* __restrict__ out) {
    int idx = blockIdx.x * blockDim.x + threadIdx.x;   // over N_NODES*EDIM
    if (idx >= N_NODES * EDIM) return;
    int v = idx >> 6;
    float e = (v < NUM_USERS) ? user_emb[idx] : item_emb[idx - NUM_USERS * EDIM];
    out[idx]  = e;
    embS[idx] = __float2bfloat16(dinv[v] * e);
}

// ---------------------------------------------------------------- one propagation layer (pull)
// wave per node, lane = embedding dim. embS_in[src] gathers are coalesced 128B (bf16).
template <int LAST>
__global__ void layer_kernel(const int* __restrict__ row_ptr,
                             const int* __restrict__ csr_src,
                             const float* __restrict__ dinv,
                             const __hip_bfloat16* __restrict__ embS_in,
                             __hip_bfloat16* __restrict__ embS_out,
                             float* __restrict__ out) {
    int wid  = (blockIdx.x * blockDim.x + threadIdx.x) >> 6;
    int lane = threadIdx.x & 63;
    if (wid >= N_NODES) return;
    int start = row_ptr[wid];
    int end   = row_ptr[wid + 1];
    float sum = 0.0f;
    for (int j0 = start; j0 < end; j0 += 64) {
        int idx   = j0 + lane;
        int mysrc = (idx < end) ? csr_src[idx] : 0;   // coalesced chunk of sources
        int cnt   = min(64, end - j0);
        for (int t = 0; t < cnt; ++t) {
            int src = __shfl(mysrc, t);               // wave-uniform broadcast
            sum += __bfloat162float(embS_in[(size_t)src * EDIM + lane]);
        }
    }
    float dv = dinv[wid];
    float e  = dv * sum;
    size_t o = (size_t)wid * EDIM + lane;
    if (LAST) {
        out[o] = (out[o] + e) * 0.25f;                // (acc + emb3) / (L+1)
    } else {
        out[o] += e;                                   // acc += emb_l
        embS_out[o] = __float2bfloat16(dv * e);        // state for next layer
    }
}

// ----------------------------------------------------------------
extern "C" void kernel_launch(void* const* d_in, const int* in_sizes, int n_in,
                              void* d_out, int out_size, void* d_ws, size_t ws_size,
                              hipStream_t stream) {
    const int*   ei       = (const int*)d_in[0];     // [2, E] int32
    const float* user_emb = (const float*)d_in[1];
    const float* item_emb = (const float*)d_in[2];
    float*       out      = (float*)d_out;

    char* ws = (char*)d_ws;
    size_t off = 0;
    auto alloc = [&](size_t bytes) -> void* {
        void* p = ws + off;
        off = (off + bytes + 255) & ~(size_t)255;
        return p;
    };

    int*   deg     = (int*)  alloc((size_t)N_NODES * 4);
    float* dinv    = (float*)alloc((size_t)N_NODES * 4);
    int*   lexcl   = (int*)  alloc((size_t)N_NODES * 4);
    int*   bsum    = (int*)  alloc((size_t)SCAN_NB * 4);
    int*   row_ptr = (int*)  alloc(((size_t)N_NODES + 1) * 4);
    int*   cursor  = (int*)  alloc((size_t)N_NODES * 4);
    int*   csr_src = (int*)  alloc((size_t)2 * NEDGES * 4);
    __hip_bfloat16* embS0 = (__hip_bfloat16*)alloc((size_t)N_NODES * EDIM * 2);
    __hip_bfloat16* embS1 = (__hip_bfloat16*)alloc((size_t)N_NODES * EDIM * 2);

    hipMemsetAsync(deg, 0, (size_t)N_NODES * 4, stream);

    const int B = 256;
    deg_kernel<<<(NEDGES + B - 1) / B, B, 0, stream>>>(ei, deg, NEDGES);
    dinv_kernel<<<(N_NODES + B - 1) / B, B, 0, stream>>>(deg, dinv, N_NODES);

    scan_block<<<SCAN_NB, SCAN_B, 0, stream>>>(deg, lexcl, bsum, N_NODES);
    scan_partials<<<1, 64, 0, stream>>>(bsum, SCAN_NB);
    scan_add<<<(N_NODES + B - 1) / B, B, 0, stream>>>(lexcl, bsum, row_ptr, cursor, N_NODES);

    fill_kernel<<<(NEDGES + B - 1) / B, B, 0, stream>>>(ei, cursor, csr_src, NEDGES);

    int elems = N_NODES * EDIM;
    init_kernel<<<(elems + B - 1) / B, B, 0, stream>>>(user_emb, item_emb, dinv, embS0, out);

    int lgrid = (N_NODES * 64 + B - 1) / B;   // one wave (64 lanes) per node
    layer_kernel<0><<<lgrid, B, 0, stream>>>(row_ptr, csr_src, dinv, embS0, embS1, out);
    layer_kernel<0><<<lgrid, B, 0, stream>>>(row_ptr, csr_src, dinv, embS1, embS0, out);
    layer_kernel<1><<<lgrid, B, 0, stream>>>(row_ptr, csr_src, dinv, embS0, nullptr, out);
}

// Round 3
// 311.672 us; speedup vs baseline: 2.4851x; 1.9789x over previous
//
#include <hip/hip_runtime.h>
#include <hip/hip_bf16.h>

#define NUM_USERS 60000
#define NUM_ITEMS 30000
#define N_NODES   90000
#define EDIM      64
#define NEDGES    1000000
#define SCAN_B    1024
#define SCAN_NB   ((N_NODES + SCAN_B - 1) / SCAN_B)   // 88

#define BKSZ      256                                  // nodes per bucket
#define NBUK      ((N_NODES + BKSZ - 1) / BKSZ)        // 352
#define CHUNK_E   4096                                 // edges per binA block
#define CHUNK_I   (CHUNK_E * 2)                        // directed instances

// ---------------------------------------------------------------- degree
__global__ void deg_kernel(const int* __restrict__ ei, int* __restrict__ deg, int E) {
    int i = blockIdx.x * blockDim.x + threadIdx.x;
    if (i >= E) return;
    int r = ei[i];
    int c = ei[E + i];
    atomicAdd(&deg[r], 1);
    atomicAdd(&deg[c], 1);
}

// ---------------------------------------------------------------- dinv
__global__ void dinv_kernel(const int* __restrict__ deg, float* __restrict__ dinv, int n) {
    int v = blockIdx.x * blockDim.x + threadIdx.x;
    if (v >= n) return;
    int d = deg[v];
    dinv[v] = (d > 0) ? (1.0f / sqrtf((float)d)) : 0.0f;
}

// ---------------------------------------------------------------- parallel scan stage 1
__global__ void scan_block(const int* __restrict__ deg, int* __restrict__ lexcl,
                           int* __restrict__ bsum, int n) {
    __shared__ int sdata[SCAN_B];
    int tid = threadIdx.x;
    int i = blockIdx.x * SCAN_B + tid;
    int v = (i < n) ? deg[i] : 0;
    sdata[tid] = v;
    __syncthreads();
    for (int offset = 1; offset < SCAN_B; offset <<= 1) {
        int t = (tid >= offset) ? sdata[tid - offset] : 0;
        __syncthreads();
        sdata[tid] += t;
        __syncthreads();
    }
    if (i < n) lexcl[i] = sdata[tid] - v;
    if (tid == SCAN_B - 1) bsum[blockIdx.x] = sdata[tid];
}

// ---------------------------------------------------------------- scan stage 2
__global__ void scan_partials(int* __restrict__ bsum, int nb) {
    if (threadIdx.x == 0) {
        int run = 0;
        for (int b = 0; b < nb; ++b) { int v = bsum[b]; bsum[b] = run; run += v; }
    }
}

// ---------------------------------------------------------------- scan stage 3
__global__ void scan_add(const int* __restrict__ lexcl, const int* __restrict__ bsum,
                         int* __restrict__ row_ptr, int n) {
    int i = blockIdx.x * blockDim.x + threadIdx.x;
    if (i >= n) return;
    row_ptr[i] = lexcl[i] + bsum[i >> 10];
    if (i == 0) row_ptr[n] = 2 * NEDGES;
}

// ---------------------------------------------------------------- bucket cursor init
__global__ void gcur_init(const int* __restrict__ row_ptr, int* __restrict__ gcursor) {
    int b = blockIdx.x * blockDim.x + threadIdx.x;
    if (b >= NBUK) return;
    int node = b * BKSZ;
    if (node > N_NODES) node = N_NODES;
    gcursor[b] = row_ptr[node];
}

// ---------------------------------------------------------------- pass A: bin edges by dst bucket
// staged[] is bucket-partitioned in final CSR coordinates (region b = CSR region of its nodes).
// payload u32 = src | (dst_local << 17)
__global__ void binA_kernel(const int* __restrict__ ei, int* __restrict__ gcursor,
                            unsigned int* __restrict__ staged, int E) {
    __shared__ int hist[NBUK];
    __shared__ int lexcl[NBUK + 1];
    __shared__ int cursor[NBUK];
    __shared__ int gbase[NBUK];
    __shared__ unsigned short slotbuk[CHUNK_I];
    __shared__ unsigned int   stage[CHUNK_I];

    int tid = threadIdx.x;                     // 256 threads
    int e0  = blockIdx.x * CHUNK_E;
    int ecnt = E - e0; if (ecnt > CHUNK_E) ecnt = CHUNK_E;
    int icnt = ecnt * 2;

    for (int b = tid; b < NBUK; b += 256) hist[b] = 0;
    __syncthreads();

    // 1: LDS histogram over dst buckets
    for (int k = tid; k < ecnt; k += 256) {
        int r = ei[e0 + k];
        int c = ei[E + e0 + k];
        atomicAdd(&hist[c >> 8], 1);   // instance (dst=c, src=r)
        atomicAdd(&hist[r >> 8], 1);   // instance (dst=r, src=c)
    }
    __syncthreads();

    // 2: serial exclusive scan of 352 counts
    if (tid == 0) {
        int run = 0;
        for (int b = 0; b < NBUK; ++b) { lexcl[b] = run; run += hist[b]; }
        lexcl[NBUK] = run;
    }
    __syncthreads();

    // 3: local cursors, global bases, slot->bucket map
    for (int b = tid; b < NBUK; b += 256) {
        cursor[b] = lexcl[b];
        if (hist[b] > 0) gbase[b] = atomicAdd(&gcursor[b], hist[b]);
    }
    for (int b = tid; b < NBUK; b += 256)
        for (int j = lexcl[b]; j < lexcl[b + 1]; ++j) slotbuk[j] = (unsigned short)b;
    __syncthreads();

    // 4: place instances into LDS, bucket-grouped
    for (int k = tid; k < ecnt; k += 256) {
        int r = ei[e0 + k];
        int c = ei[E + e0 + k];
        int p1 = atomicAdd(&cursor[c >> 8], 1);
        stage[p1] = (unsigned int)r | ((unsigned int)(c & (BKSZ - 1)) << 17);
        int p2 = atomicAdd(&cursor[r >> 8], 1);
        stage[p2] = (unsigned int)c | ((unsigned int)(r & (BKSZ - 1)) << 17);
    }
    __syncthreads();

    // 5: coalesced write-out (consecutive slots -> consecutive global addrs per run)
    for (int j = tid; j < icnt; j += 256) {
        int b = slotbuk[j];
        staged[gbase[b] + (j - lexcl[b])] = stage[j];
    }
}

// ---------------------------------------------------------------- pass B: place within bucket
__global__ void binB_kernel(const int* __restrict__ row_ptr,
                            const unsigned int* __restrict__ staged,
                            int* __restrict__ csr_src) {
    __shared__ int cur[BKSZ];
    int b = blockIdx.x;
    int node0 = b * BKSZ;
    int nn = N_NODES - node0; if (nn > BKSZ) nn = BKSZ;
    if (nn <= 0) return;
    int tid = threadIdx.x;                      // 256 threads
    for (int i = tid; i < nn; i += 256) cur[i] = row_ptr[node0 + i];
    __syncthreads();
    int base = row_ptr[node0];
    int cnt  = row_ptr[node0 + nn] - base;
    for (int j = tid; j < cnt; j += 256) {
        unsigned int v = staged[base + j];
        int src = (int)(v & 0x1FFFFu);
        int dl  = (int)(v >> 17);
        int pos = atomicAdd(&cur[dl], 1);
        csr_src[pos] = src;                     // scattered only within ~23KB region
    }
}

// ---------------------------------------------------------------- init embS0 = bf16(dinv*emb0), acc = emb0
__global__ void init_kernel(const float* __restrict__ user_emb,
                            const float* __restrict__ item_emb,
                            const float* __restrict__ dinv,
                            __hip_bfloat16* __restrict__ embS, float* __restrict__ out) {
    int idx = blockIdx.x * blockDim.x + threadIdx.x;
    if (idx >= N_NODES * EDIM) return;
    int v = idx >> 6;
    float e = (v < NUM_USERS) ? user_emb[idx] : item_emb[idx - NUM_USERS * EDIM];
    out[idx]  = e;
    embS[idx] = __float2bfloat16(dinv[v] * e);
}

// ---------------------------------------------------------------- propagation layer (pull)
template <int LAST>
__global__ void layer_kernel(const int* __restrict__ row_ptr,
                             const int* __restrict__ csr_src,
                             const float* __restrict__ dinv,
                             const __hip_bfloat16* __restrict__ embS_in,
                             __hip_bfloat16* __restrict__ embS_out,
                             float* __restrict__ out) {
    int wid  = (blockIdx.x * blockDim.x + threadIdx.x) >> 6;
    int lane = threadIdx.x & 63;
    if (wid >= N_NODES) return;
    int start = row_ptr[wid];
    int end   = row_ptr[wid + 1];
    float s0 = 0.0f, s1 = 0.0f, s2 = 0.0f, s3 = 0.0f;
    for (int j0 = start; j0 < end; j0 += 64) {
        int idx   = j0 + lane;
        int mysrc = (idx < end) ? csr_src[idx] : 0;
        int cnt   = min(64, end - j0);
        int t = 0;
        // 8-wide batches: 8 independent gathers in flight, 4 partial sums
        for (; t + 8 <= cnt; t += 8) {
            float v[8];
            #pragma unroll
            for (int u = 0; u < 8; ++u) {
                int src = __shfl(mysrc, t + u);
                v[u] = __bfloat162float(embS_in[(size_t)src * EDIM + lane]);
            }
            s0 += v[0]; s1 += v[1]; s2 += v[2]; s3 += v[3];
            s0 += v[4]; s1 += v[5]; s2 += v[6]; s3 += v[7];
        }
        for (; t < cnt; ++t) {
            int src = __shfl(mysrc, t);
            s0 += __bfloat162float(embS_in[(size_t)src * EDIM + lane]);
        }
    }
    float sum = (s0 + s1) + (s2 + s3);
    float dv = dinv[wid];
    float e  = dv * sum;
    size_t o = (size_t)wid * EDIM + lane;
    if (LAST) {
        out[o] = (out[o] + e) * 0.25f;
    } else {
        out[o] += e;
        embS_out[o] = __float2bfloat16(dv * e);
    }
}

// ----------------------------------------------------------------
extern "C" void kernel_launch(void* const* d_in, const int* in_sizes, int n_in,
                              void* d_out, int out_size, void* d_ws, size_t ws_size,
                              hipStream_t stream) {
    const int*   ei       = (const int*)d_in[0];
    const float* user_emb = (const float*)d_in[1];
    const float* item_emb = (const float*)d_in[2];
    float*       out      = (float*)d_out;

    char* ws = (char*)d_ws;
    size_t off = 0;
    auto alloc = [&](size_t bytes) -> void* {
        void* p = ws + off;
        off = (off + bytes + 255) & ~(size_t)255;
        return p;
    };

    int*   deg     = (int*)  alloc((size_t)N_NODES * 4);
    float* dinv    = (float*)alloc((size_t)N_NODES * 4);
    int*   lexcl   = (int*)  alloc((size_t)N_NODES * 4);
    int*   bsum    = (int*)  alloc((size_t)SCAN_NB * 4);
    int*   row_ptr = (int*)  alloc(((size_t)N_NODES + 1) * 4);
    int*   gcursor = (int*)  alloc((size_t)NBUK * 4);
    unsigned int* staged = (unsigned int*)alloc((size_t)2 * NEDGES * 4);
    int*   csr_src = (int*)  alloc((size_t)2 * NEDGES * 4);
    __hip_bfloat16* embS0 = (__hip_bfloat16*)alloc((size_t)N_NODES * EDIM * 2);
    __hip_bfloat16* embS1 = (__hip_bfloat16*)alloc((size_t)N_NODES * EDIM * 2);

    hipMemsetAsync(deg, 0, (size_t)N_NODES * 4, stream);

    const int B = 256;
    deg_kernel<<<(NEDGES + B - 1) / B, B, 0, stream>>>(ei, deg, NEDGES);
    dinv_kernel<<<(N_NODES + B - 1) / B, B, 0, stream>>>(deg, dinv, N_NODES);

    scan_block<<<SCAN_NB, SCAN_B, 0, stream>>>(deg, lexcl, bsum, N_NODES);
    scan_partials<<<1, 64, 0, stream>>>(bsum, SCAN_NB);
    scan_add<<<(N_NODES + B - 1) / B, B, 0, stream>>>(lexcl, bsum, row_ptr, N_NODES);

    gcur_init<<<(NBUK + B - 1) / B, B, 0, stream>>>(row_ptr, gcursor);
    binA_kernel<<<(NEDGES + CHUNK_E - 1) / CHUNK_E, B, 0, stream>>>(ei, gcursor, staged, NEDGES);
    binB_kernel<<<NBUK, B, 0, stream>>>(row_ptr, staged, csr_src);

    int elems = N_NODES * EDIM;
    init_kernel<<<(elems + B - 1) / B, B, 0, stream>>>(user_emb, item_emb, dinv, embS0, out);

    int lgrid = (N_NODES * 64 + B - 1) / B;
    layer_kernel<0><<<lgrid, B, 0, stream>>>(row_ptr, csr_src, dinv, embS0, embS1, out);
    layer_kernel<0><<<lgrid, B, 0, stream>>>(row_ptr, csr_src, dinv, embS1, embS0, out);
    layer_kernel<1><<<lgrid, B, 0, stream>>>(row_ptr, csr_src, dinv, embS0, nullptr, out);
}

// Round 4
// 234.916 us; speedup vs baseline: 3.2971x; 1.3267x over previous
//
#include <hip/hip_runtime.h>
#include <hip/hip_bf16.h>

#define NUM_USERS 60000
#define NUM_ITEMS 30000
#define N_NODES   90000
#define EDIM      64
#define NEDGES    1000000

#define BKSZ      256                                  // nodes per bucket
#define NBUK      ((N_NODES + BKSZ - 1) / BKSZ)        // 352
#define CHUNK_E   4096                                 // edges per binning block
#define CHUNK_I   (CHUNK_E * 2)                        // directed instances

// ---------------------------------------------------------------- pass A1: bucket-count histogram
// LDS-aggregated: 352 global atomics per block instead of 2 per edge.
__global__ void histA_kernel(const int* __restrict__ ei, int* __restrict__ bucket_cnt, int E) {
    __shared__ int hist[NBUK];
    int tid = threadIdx.x;
    for (int b = tid; b < NBUK; b += 256) hist[b] = 0;
    __syncthreads();
    int e0 = blockIdx.x * CHUNK_E;
    int ecnt = E - e0; if (ecnt > CHUNK_E) ecnt = CHUNK_E;
    for (int k = tid; k < ecnt; k += 256) {
        int r = ei[e0 + k];
        int c = ei[E + e0 + k];
        atomicAdd(&hist[c >> 8], 1);   // instance (dst=c)
        atomicAdd(&hist[r >> 8], 1);   // instance (dst=r)
    }
    __syncthreads();
    for (int b = tid; b < NBUK; b += 256)
        if (hist[b] > 0) atomicAdd(&bucket_cnt[b], hist[b]);
}

// ---------------------------------------------------------------- bucket scan (352 values, trivial)
__global__ void bscan_kernel(const int* __restrict__ bucket_cnt,
                             int* __restrict__ bucket_base, int* __restrict__ gcursor) {
    if (threadIdx.x == 0) {
        int run = 0;
        for (int b = 0; b < NBUK; ++b) {
            bucket_base[b] = run;
            gcursor[b]     = run;
            run += bucket_cnt[b];
        }
        bucket_base[NBUK] = run;   // == 2*NEDGES
    }
}

// ---------------------------------------------------------------- pass A2: bin edges by dst bucket
// staged[] is bucket-partitioned in final CSR coordinates.
// payload u32 = src | (dst_local << 17)
__global__ void binA_kernel(const int* __restrict__ ei, int* __restrict__ gcursor,
                            unsigned int* __restrict__ staged, int E) {
    __shared__ int hist[NBUK];
    __shared__ int lexcl[NBUK + 1];
    __shared__ int cursor[NBUK];
    __shared__ int gbase[NBUK];
    __shared__ unsigned short slotbuk[CHUNK_I];
    __shared__ unsigned int   stage[CHUNK_I];

    int tid = threadIdx.x;                     // 256 threads
    int e0  = blockIdx.x * CHUNK_E;
    int ecnt = E - e0; if (ecnt > CHUNK_E) ecnt = CHUNK_E;
    int icnt = ecnt * 2;

    for (int b = tid; b < NBUK; b += 256) hist[b] = 0;
    __syncthreads();

    // 1: LDS histogram over dst buckets
    for (int k = tid; k < ecnt; k += 256) {
        int r = ei[e0 + k];
        int c = ei[E + e0 + k];
        atomicAdd(&hist[c >> 8], 1);
        atomicAdd(&hist[r >> 8], 1);
    }
    __syncthreads();

    // 2: serial exclusive scan of 352 counts
    if (tid == 0) {
        int run = 0;
        for (int b = 0; b < NBUK; ++b) { lexcl[b] = run; run += hist[b]; }
        lexcl[NBUK] = run;
    }
    __syncthreads();

    // 3: local cursors, global bases, slot->bucket map
    for (int b = tid; b < NBUK; b += 256) {
        cursor[b] = lexcl[b];
        if (hist[b] > 0) gbase[b] = atomicAdd(&gcursor[b], hist[b]);
    }
    for (int b = tid; b < NBUK; b += 256)
        for (int j = lexcl[b]; j < lexcl[b + 1]; ++j) slotbuk[j] = (unsigned short)b;
    __syncthreads();

    // 4: place instances into LDS, bucket-grouped
    for (int k = tid; k < ecnt; k += 256) {
        int r = ei[e0 + k];
        int c = ei[E + e0 + k];
        int p1 = atomicAdd(&cursor[c >> 8], 1);
        stage[p1] = (unsigned int)r | ((unsigned int)(c & (BKSZ - 1)) << 17);
        int p2 = atomicAdd(&cursor[r >> 8], 1);
        stage[p2] = (unsigned int)c | ((unsigned int)(r & (BKSZ - 1)) << 17);
    }
    __syncthreads();

    // 5: coalesced write-out (consecutive slots -> consecutive global addrs per run)
    for (int j = tid; j < icnt; j += 256) {
        int b = slotbuk[j];
        staged[gbase[b] + (j - lexcl[b])] = stage[j];
    }
}

// ---------------------------------------------------------------- pass B: per-bucket finalize
// Derives per-node degree from staged payloads (LDS), writes row_ptr + dinv + csr_src.
__global__ void binB_kernel(const int* __restrict__ bucket_base,
                            const unsigned int* __restrict__ staged,
                            int* __restrict__ csr_src, int* __restrict__ row_ptr,
                            float* __restrict__ dinv) {
    __shared__ int deghist[BKSZ];
    __shared__ int lpre[BKSZ];
    __shared__ int cur[BKSZ];
    int b = blockIdx.x;
    int node0 = b * BKSZ;
    int nn = N_NODES - node0; if (nn > BKSZ) nn = BKSZ;
    int tid = threadIdx.x;                      // 256 threads == BKSZ
    deghist[tid] = 0;
    __syncthreads();
    int base = bucket_base[b];
    int cnt  = bucket_base[b + 1] - base;
    for (int j = tid; j < cnt; j += 256) {
        unsigned int v = staged[base + j];
        atomicAdd(&deghist[v >> 17], 1);
    }
    __syncthreads();
    // Hillis-Steele inclusive scan of 256 degrees
    int myv = deghist[tid];
    lpre[tid] = myv;
    __syncthreads();
    for (int off = 1; off < BKSZ; off <<= 1) {
        int t = (tid >= off) ? lpre[tid - off] : 0;
        __syncthreads();
        lpre[tid] += t;
        __syncthreads();
    }
    int excl = lpre[tid] - myv;
    cur[tid] = base + excl;
    if (tid < nn) {
        row_ptr[node0 + tid] = base + excl;
        dinv[node0 + tid] = (myv > 0) ? (1.0f / sqrtf((float)myv)) : 0.0f;
    }
    if (b == NBUK - 1 && tid == 0) row_ptr[N_NODES] = base + cnt;
    __syncthreads();
    for (int j = tid; j < cnt; j += 256) {
        unsigned int v = staged[base + j];
        int pos = atomicAdd(&cur[v >> 17], 1);
        csr_src[pos] = (int)(v & 0x1FFFFu);     // scattered only within ~23KB region
    }
}

// ---------------------------------------------------------------- init embS0 = bf16(dinv*emb0), acc = emb0
__global__ void init_kernel(const float* __restrict__ user_emb,
                            const float* __restrict__ item_emb,
                            const float* __restrict__ dinv,
                            __hip_bfloat16* __restrict__ embS, float* __restrict__ out) {
    int idx = blockIdx.x * blockDim.x + threadIdx.x;
    if (idx >= N_NODES * EDIM) return;
    int v = idx >> 6;
    float e = (v < NUM_USERS) ? user_emb[idx] : item_emb[idx - NUM_USERS * EDIM];
    out[idx]  = e;
    embS[idx] = __float2bfloat16(dinv[v] * e);
}

// ---------------------------------------------------------------- propagation layer (pull)
template <int LAST>
__global__ void layer_kernel(const int* __restrict__ row_ptr,
                             const int* __restrict__ csr_src,
                             const float* __restrict__ dinv,
                             const __hip_bfloat16* __restrict__ embS_in,
                             __hip_bfloat16* __restrict__ embS_out,
                             float* __restrict__ out) {
    int wid  = (blockIdx.x * blockDim.x + threadIdx.x) >> 6;
    int lane = threadIdx.x & 63;
    if (wid >= N_NODES) return;
    int start = row_ptr[wid];
    int end   = row_ptr[wid + 1];
    float s0 = 0.0f, s1 = 0.0f, s2 = 0.0f, s3 = 0.0f;
    for (int j0 = start; j0 < end; j0 += 64) {
        int idx   = j0 + lane;
        int mysrc = (idx < end) ? csr_src[idx] : 0;
        int cnt   = min(64, end - j0);
        int t = 0;
        for (; t + 8 <= cnt; t += 8) {
            float v[8];
            #pragma unroll
            for (int u = 0; u < 8; ++u) {
                int src = __shfl(mysrc, t + u);
                v[u] = __bfloat162float(embS_in[(size_t)src * EDIM + lane]);
            }
            s0 += v[0]; s1 += v[1]; s2 += v[2]; s3 += v[3];
            s0 += v[4]; s1 += v[5]; s2 += v[6]; s3 += v[7];
        }
        for (; t < cnt; ++t) {
            int src = __shfl(mysrc, t);
            s0 += __bfloat162float(embS_in[(size_t)src * EDIM + lane]);
        }
    }
    float sum = (s0 + s1) + (s2 + s3);
    float dv = dinv[wid];
    float e  = dv * sum;
    size_t o = (size_t)wid * EDIM + lane;
    if (LAST) {
        out[o] = (out[o] + e) * 0.25f;
    } else {
        out[o] += e;
        embS_out[o] = __float2bfloat16(dv * e);
    }
}

// ----------------------------------------------------------------
extern "C" void kernel_launch(void* const* d_in, const int* in_sizes, int n_in,
                              void* d_out, int out_size, void* d_ws, size_t ws_size,
                              hipStream_t stream) {
    const int*   ei       = (const int*)d_in[0];
    const float* user_emb = (const float*)d_in[1];
    const float* item_emb = (const float*)d_in[2];
    float*       out      = (float*)d_out;

    char* ws = (char*)d_ws;
    size_t off = 0;
    auto alloc = [&](size_t bytes) -> void* {
        void* p = ws + off;
        off = (off + bytes + 255) & ~(size_t)255;
        return p;
    };

    int*   bucket_cnt  = (int*)  alloc((size_t)NBUK * 4);
    int*   bucket_base = (int*)  alloc(((size_t)NBUK + 1) * 4);
    int*   gcursor     = (int*)  alloc((size_t)NBUK * 4);
    int*   row_ptr     = (int*)  alloc(((size_t)N_NODES + 1) * 4);
    float* dinv        = (float*)alloc((size_t)N_NODES * 4);
    unsigned int* staged = (unsigned int*)alloc((size_t)2 * NEDGES * 4);
    int*   csr_src     = (int*)  alloc((size_t)2 * NEDGES * 4);
    __hip_bfloat16* embS0 = (__hip_bfloat16*)alloc((size_t)N_NODES * EDIM * 2);
    __hip_bfloat16* embS1 = (__hip_bfloat16*)alloc((size_t)N_NODES * EDIM * 2);

    hipMemsetAsync(bucket_cnt, 0, (size_t)NBUK * 4, stream);

    const int B = 256;
    int nbin = (NEDGES + CHUNK_E - 1) / CHUNK_E;   // 245
    histA_kernel<<<nbin, B, 0, stream>>>(ei, bucket_cnt, NEDGES);
    bscan_kernel<<<1, 64, 0, stream>>>(bucket_cnt, bucket_base, gcursor);
    binA_kernel<<<nbin, B, 0, stream>>>(ei, gcursor, staged, NEDGES);
    binB_kernel<<<NBUK, B, 0, stream>>>(bucket_base, staged, csr_src, row_ptr, dinv);

    int elems = N_NODES * EDIM;
    init_kernel<<<(elems + B - 1) / B, B, 0, stream>>>(user_emb, item_emb, dinv, embS0, out);

    int lgrid = (N_NODES * 64 + B - 1) / B;   // one wave (64 lanes) per node
    layer_kernel<0><<<lgrid, B, 0, stream>>>(row_ptr, csr_src, dinv, embS0, embS1, out);
    layer_kernel<0><<<lgrid, B, 0, stream>>>(row_ptr, csr_src, dinv, embS1, embS0, out);
    layer_kernel<1><<<lgrid, B, 0, stream>>>(row_ptr, csr_src, dinv, embS0, nullptr, out);
}

// Round 5
// 229.093 us; speedup vs baseline: 3.3809x; 1.0254x over previous
//
#include <hip/hip_runtime.h>
#include <hip/hip_bf16.h>

#define NUM_USERS 60000
#define NUM_ITEMS 30000
#define N_NODES   90000
#define EDIM      64
#define NEDGES    1000000

#define BKSZ      256                                  // nodes per bucket
#define NBUK      ((N_NODES + BKSZ - 1) / BKSZ)        // 352
#define CHUNK_E   4096                                 // edges per binning block
#define CHUNK_I   (CHUNK_E * 2)                        // directed instances

// bf16 helpers: unpack via shift (exact), pack via RNE
__device__ __forceinline__ float bf_lo(unsigned int u) {
    return __builtin_bit_cast(float, u << 16);
}
__device__ __forceinline__ float bf_hi(unsigned int u) {
    return __builtin_bit_cast(float, u & 0xffff0000u);
}
__device__ __forceinline__ unsigned int f2bf(float f) {
    unsigned int u = __builtin_bit_cast(unsigned int, f);
    return (u + 0x7fffu + ((u >> 16) & 1u)) >> 16;      // RNE to bf16 bits
}

// ---------------------------------------------------------------- pass A1: bucket-count histogram
__global__ void histA_kernel(const int* __restrict__ ei, int* __restrict__ bucket_cnt, int E) {
    __shared__ int hist[NBUK];
    int tid = threadIdx.x;
    for (int b = tid; b < NBUK; b += 256) hist[b] = 0;
    __syncthreads();
    int e0 = blockIdx.x * CHUNK_E;
    int ecnt = E - e0; if (ecnt > CHUNK_E) ecnt = CHUNK_E;
    for (int k = tid; k < ecnt; k += 256) {
        int r = ei[e0 + k];
        int c = ei[E + e0 + k];
        atomicAdd(&hist[c >> 8], 1);
        atomicAdd(&hist[r >> 8], 1);
    }
    __syncthreads();
    for (int b = tid; b < NBUK; b += 256)
        if (hist[b] > 0) atomicAdd(&bucket_cnt[b], hist[b]);
}

// ---------------------------------------------------------------- bucket scan (352 values)
__global__ void bscan_kernel(const int* __restrict__ bucket_cnt,
                             int* __restrict__ bucket_base, int* __restrict__ gcursor) {
    if (threadIdx.x == 0) {
        int run = 0;
        for (int b = 0; b < NBUK; ++b) {
            bucket_base[b] = run;
            gcursor[b]     = run;
            run += bucket_cnt[b];
        }
        bucket_base[NBUK] = run;   // == 2*NEDGES
    }
}

// ---------------------------------------------------------------- pass A2: bin edges by dst bucket
// payload u32 = src | (dst_local << 17)
__global__ void binA_kernel(const int* __restrict__ ei, int* __restrict__ gcursor,
                            unsigned int* __restrict__ staged, int E) {
    __shared__ int hist[NBUK];
    __shared__ int lexcl[NBUK + 1];
    __shared__ int cursor[NBUK];
    __shared__ int gbase[NBUK];
    __shared__ unsigned short slotbuk[CHUNK_I];
    __shared__ unsigned int   stage[CHUNK_I];

    int tid = threadIdx.x;
    int e0  = blockIdx.x * CHUNK_E;
    int ecnt = E - e0; if (ecnt > CHUNK_E) ecnt = CHUNK_E;
    int icnt = ecnt * 2;

    for (int b = tid; b < NBUK; b += 256) hist[b] = 0;
    __syncthreads();

    for (int k = tid; k < ecnt; k += 256) {
        int r = ei[e0 + k];
        int c = ei[E + e0 + k];
        atomicAdd(&hist[c >> 8], 1);
        atomicAdd(&hist[r >> 8], 1);
    }
    __syncthreads();

    if (tid == 0) {
        int run = 0;
        for (int b = 0; b < NBUK; ++b) { lexcl[b] = run; run += hist[b]; }
        lexcl[NBUK] = run;
    }
    __syncthreads();

    for (int b = tid; b < NBUK; b += 256) {
        cursor[b] = lexcl[b];
        if (hist[b] > 0) gbase[b] = atomicAdd(&gcursor[b], hist[b]);
    }
    for (int b = tid; b < NBUK; b += 256)
        for (int j = lexcl[b]; j < lexcl[b + 1]; ++j) slotbuk[j] = (unsigned short)b;
    __syncthreads();

    for (int k = tid; k < ecnt; k += 256) {
        int r = ei[e0 + k];
        int c = ei[E + e0 + k];
        int p1 = atomicAdd(&cursor[c >> 8], 1);
        stage[p1] = (unsigned int)r | ((unsigned int)(c & (BKSZ - 1)) << 17);
        int p2 = atomicAdd(&cursor[r >> 8], 1);
        stage[p2] = (unsigned int)c | ((unsigned int)(r & (BKSZ - 1)) << 17);
    }
    __syncthreads();

    for (int j = tid; j < icnt; j += 256) {
        int b = slotbuk[j];
        staged[gbase[b] + (j - lexcl[b])] = stage[j];
    }
}

// ---------------------------------------------------------------- pass B: per-bucket finalize
__global__ void binB_kernel(const int* __restrict__ bucket_base,
                            const unsigned int* __restrict__ staged,
                            int* __restrict__ csr_src, int* __restrict__ row_ptr,
                            float* __restrict__ dinv) {
    __shared__ int deghist[BKSZ];
    __shared__ int lpre[BKSZ];
    __shared__ int cur[BKSZ];
    int b = blockIdx.x;
    int node0 = b * BKSZ;
    int nn = N_NODES - node0; if (nn > BKSZ) nn = BKSZ;
    int tid = threadIdx.x;
    deghist[tid] = 0;
    __syncthreads();
    int base = bucket_base[b];
    int cnt  = bucket_base[b + 1] - base;
    for (int j = tid; j < cnt; j += 256) {
        unsigned int v = staged[base + j];
        atomicAdd(&deghist[v >> 17], 1);
    }
    __syncthreads();
    int myv = deghist[tid];
    lpre[tid] = myv;
    __syncthreads();
    for (int off = 1; off < BKSZ; off <<= 1) {
        int t = (tid >= off) ? lpre[tid - off] : 0;
        __syncthreads();
        lpre[tid] += t;
        __syncthreads();
    }
    int excl = lpre[tid] - myv;
    cur[tid] = base + excl;
    if (tid < nn) {
        row_ptr[node0 + tid] = base + excl;
        dinv[node0 + tid] = (myv > 0) ? (1.0f / sqrtf((float)myv)) : 0.0f;
    }
    if (b == NBUK - 1 && tid == 0) row_ptr[N_NODES] = base + cnt;
    __syncthreads();
    for (int j = tid; j < cnt; j += 256) {
        unsigned int v = staged[base + j];
        int pos = atomicAdd(&cur[v >> 17], 1);
        csr_src[pos] = (int)(v & 0x1FFFFu);
    }
}

// ---------------------------------------------------------------- init: vectorized float4/uint2
// thread = one float4 (4 dims); writes acc(out) and embS0 = bf16(dinv*emb)
__global__ void init_kernel(const float* __restrict__ user_emb,
                            const float* __restrict__ item_emb,
                            const float* __restrict__ dinv,
                            unsigned int* __restrict__ embS, float* __restrict__ out) {
    int i = blockIdx.x * blockDim.x + threadIdx.x;   // over N_NODES*16 float4 units
    if (i >= N_NODES * 16) return;
    int v = i >> 4;
    float4 e = (v < NUM_USERS) ? ((const float4*)user_emb)[i]
                               : ((const float4*)item_emb)[i - NUM_USERS * 16];
    ((float4*)out)[i] = e;
    float dv = dinv[v];
    uint2 p;
    p.x = f2bf(dv * e.x) | (f2bf(dv * e.y) << 16);
    p.y = f2bf(dv * e.z) | (f2bf(dv * e.w) << 16);
    ((uint2*)embS)[i] = p;
}

// ---------------------------------------------------------------- propagation layer (pull)
// wave per node; 4 groups of 16 lanes, each group gathers a different source per
// iteration (uint2 = 4 dims/lane). Cross-group shfl_xor reduce at the end.
template <int LAST>
__global__ void layer_kernel(const int* __restrict__ row_ptr,
                             const int* __restrict__ csr_src,
                             const float* __restrict__ dinv,
                             const unsigned int* __restrict__ embS_in,   // bf16x2 words
                             unsigned int* __restrict__ embS_out,
                             float* __restrict__ out) {
    int wid  = (blockIdx.x * blockDim.x + threadIdx.x) >> 6;
    int lane = threadIdx.x & 63;
    if (wid >= N_NODES) return;
    int g  = lane >> 4;          // source slot within iteration (0..3)
    int sl = lane & 15;          // dims 4*sl .. 4*sl+3
    int start = row_ptr[wid];
    int end   = row_ptr[wid + 1];
    float s0 = 0.f, s1 = 0.f, s2 = 0.f, s3 = 0.f;

    const uint2* tab = (const uint2*)embS_in;   // row = 16 uint2

    for (int j0 = start; j0 < end; j0 += 64) {
        int idx   = j0 + lane;
        int mysrc = (idx < end) ? csr_src[idx] : 0;
        int cnt   = min(64, end - j0);
        int t = 0;
        #pragma unroll 2
        for (; t + 4 <= cnt; t += 4) {           // full iterations: no guards
            int src = __shfl(mysrc, t + g);      // one ds_bpermute, per-lane index
            uint2 u = tab[((size_t)src << 4) + sl];
            s0 += bf_lo(u.x); s1 += bf_hi(u.x);
            s2 += bf_lo(u.y); s3 += bf_hi(u.y);
        }
        if (t < cnt) {                           // predicated tail
            int tt  = t + g;
            int src = __shfl(mysrc, min(tt, cnt - 1));
            uint2 u = tab[((size_t)src << 4) + sl];
            unsigned int m = (tt < cnt) ? 0xffffffffu : 0u;
            u.x &= m; u.y &= m;
            s0 += bf_lo(u.x); s1 += bf_hi(u.x);
            s2 += bf_lo(u.y); s3 += bf_hi(u.y);
        }
    }

    // sum the 4 lane-groups (lanes differing in bits 4,5)
    s0 += __shfl_xor(s0, 16); s0 += __shfl_xor(s0, 32);
    s1 += __shfl_xor(s1, 16); s1 += __shfl_xor(s1, 32);
    s2 += __shfl_xor(s2, 16); s2 += __shfl_xor(s2, 32);
    s3 += __shfl_xor(s3, 16); s3 += __shfl_xor(s3, 32);

    if (lane < 16) {
        float dv = dinv[wid];
        float e0 = dv * s0, e1 = dv * s1, e2 = dv * s2, e3 = dv * s3;
        size_t o4 = (size_t)wid * 16 + sl;       // float4 index
        float4 prev = ((const float4*)out)[o4];
        float4 w;
        if (LAST) {
            w.x = (prev.x + e0) * 0.25f;
            w.y = (prev.y + e1) * 0.25f;
            w.z = (prev.z + e2) * 0.25f;
            w.w = (prev.w + e3) * 0.25f;
            ((float4*)out)[o4] = w;
        } else {
            w.x = prev.x + e0; w.y = prev.y + e1;
            w.z = prev.z + e2; w.w = prev.w + e3;
            ((float4*)out)[o4] = w;
            uint2 p;                              // embS_out = bf16(dv*e) = dv^2 * sum
            p.x = f2bf(dv * e0) | (f2bf(dv * e1) << 16);
            p.y = f2bf(dv * e2) | (f2bf(dv * e3) << 16);
            ((uint2*)embS_out)[o4] = p;
        }
    }
}

// ----------------------------------------------------------------
extern "C" void kernel_launch(void* const* d_in, const int* in_sizes, int n_in,
                              void* d_out, int out_size, void* d_ws, size_t ws_size,
                              hipStream_t stream) {
    const int*   ei       = (const int*)d_in[0];
    const float* user_emb = (const float*)d_in[1];
    const float* item_emb = (const float*)d_in[2];
    float*       out      = (float*)d_out;

    char* ws = (char*)d_ws;
    size_t off = 0;
    auto alloc = [&](size_t bytes) -> void* {
        void* p = ws + off;
        off = (off + bytes + 255) & ~(size_t)255;
        return p;
    };

    int*   bucket_cnt  = (int*)  alloc((size_t)NBUK * 4);
    int*   bucket_base = (int*)  alloc(((size_t)NBUK + 1) * 4);
    int*   gcursor     = (int*)  alloc((size_t)NBUK * 4);
    int*   row_ptr     = (int*)  alloc(((size_t)N_NODES + 1) * 4);
    float* dinv        = (float*)alloc((size_t)N_NODES * 4);
    unsigned int* staged = (unsigned int*)alloc((size_t)2 * NEDGES * 4);
    int*   csr_src     = (int*)  alloc((size_t)2 * NEDGES * 4);
    unsigned int* embS0 = (unsigned int*)alloc((size_t)N_NODES * EDIM * 2);
    unsigned int* embS1 = (unsigned int*)alloc((size_t)N_NODES * EDIM * 2);

    hipMemsetAsync(bucket_cnt, 0, (size_t)NBUK * 4, stream);

    const int B = 256;
    int nbin = (NEDGES + CHUNK_E - 1) / CHUNK_E;   // 245
    histA_kernel<<<nbin, B, 0, stream>>>(ei, bucket_cnt, NEDGES);
    bscan_kernel<<<1, 64, 0, stream>>>(bucket_cnt, bucket_base, gcursor);
    binA_kernel<<<nbin, B, 0, stream>>>(ei, gcursor, staged, NEDGES);
    binB_kernel<<<NBUK, B, 0, stream>>>(bucket_base, staged, csr_src, row_ptr, dinv);

    init_kernel<<<(N_NODES * 16 + B - 1) / B, B, 0, stream>>>(user_emb, item_emb, dinv, embS0, out);

    int lgrid = (N_NODES * 64 + B - 1) / B;   // one wave (64 lanes) per node
    layer_kernel<0><<<lgrid, B, 0, stream>>>(row_ptr, csr_src, dinv, embS0, embS1, out);
    layer_kernel<0><<<lgrid, B, 0, stream>>>(row_ptr, csr_src, dinv, embS1, embS0, out);
    layer_kernel<1><<<lgrid, B, 0, stream>>>(row_ptr, csr_src, dinv, embS0, nullptr, out);
}

// Round 6
// 223.857 us; speedup vs baseline: 3.4600x; 1.0234x over previous
//
#include <hip/hip_runtime.h>
#include <hip/hip_bf16.h>

#define NUM_USERS 60000
#define NUM_ITEMS 30000
#define N_NODES   90000
#define EDIM      64
#define NEDGES    1000000

#define BKSZ      256                                  // nodes per bucket
#define NBUK      ((N_NODES + BKSZ - 1) / BKSZ)        // 352
#define CHUNK_E   4096                                 // edges per binning block
#define CHUNK_I   (CHUNK_E * 2)                        // directed instances

// bf16 helpers: unpack via shift (exact), pack via RNE
__device__ __forceinline__ float bf_lo(unsigned int u) {
    return __builtin_bit_cast(float, u << 16);
}
__device__ __forceinline__ float bf_hi(unsigned int u) {
    return __builtin_bit_cast(float, u & 0xffff0000u);
}
__device__ __forceinline__ unsigned int f2bf(float f) {
    unsigned int u = __builtin_bit_cast(unsigned int, f);
    return (u + 0x7fffu + ((u >> 16) & 1u)) >> 16;      // RNE to bf16 bits
}

// ---------------------------------------------------------------- pass A1: bucket-count histogram
__global__ void histA_kernel(const int* __restrict__ ei, int* __restrict__ bucket_cnt, int E) {
    __shared__ int hist[NBUK];
    int tid = threadIdx.x;
    for (int b = tid; b < NBUK; b += 256) hist[b] = 0;
    __syncthreads();
    int e0 = blockIdx.x * CHUNK_E;
    int ecnt = E - e0; if (ecnt > CHUNK_E) ecnt = CHUNK_E;
    for (int k = tid; k < ecnt; k += 256) {
        int r = ei[e0 + k];
        int c = ei[E + e0 + k];
        atomicAdd(&hist[c >> 8], 1);
        atomicAdd(&hist[r >> 8], 1);
    }
    __syncthreads();
    for (int b = tid; b < NBUK; b += 256)
        if (hist[b] > 0) atomicAdd(&bucket_cnt[b], hist[b]);
}

// ---------------------------------------------------------------- bucket scan (352 values)
__global__ void bscan_kernel(const int* __restrict__ bucket_cnt,
                             int* __restrict__ bucket_base, int* __restrict__ gcursor) {
    if (threadIdx.x == 0) {
        int run = 0;
        for (int b = 0; b < NBUK; ++b) {
            bucket_base[b] = run;
            gcursor[b]     = run;
            run += bucket_cnt[b];
        }
        bucket_base[NBUK] = run;   // == 2*NEDGES
    }
}

// ---------------------------------------------------------------- pass A2: bin edges by dst bucket
// payload u32 = src | (dst_local << 17)
__global__ void binA_kernel(const int* __restrict__ ei, int* __restrict__ gcursor,
                            unsigned int* __restrict__ staged, int E) {
    __shared__ int hist[NBUK];
    __shared__ int lexcl[NBUK + 1];
    __shared__ int cursor[NBUK];
    __shared__ int gbase[NBUK];
    __shared__ unsigned short slotbuk[CHUNK_I];
    __shared__ unsigned int   stage[CHUNK_I];

    int tid = threadIdx.x;
    int e0  = blockIdx.x * CHUNK_E;
    int ecnt = E - e0; if (ecnt > CHUNK_E) ecnt = CHUNK_E;
    int icnt = ecnt * 2;

    for (int b = tid; b < NBUK; b += 256) hist[b] = 0;
    __syncthreads();

    for (int k = tid; k < ecnt; k += 256) {
        int r = ei[e0 + k];
        int c = ei[E + e0 + k];
        atomicAdd(&hist[c >> 8], 1);
        atomicAdd(&hist[r >> 8], 1);
    }
    __syncthreads();

    if (tid == 0) {
        int run = 0;
        for (int b = 0; b < NBUK; ++b) { lexcl[b] = run; run += hist[b]; }
        lexcl[NBUK] = run;
    }
    __syncthreads();

    for (int b = tid; b < NBUK; b += 256) {
        cursor[b] = lexcl[b];
        if (hist[b] > 0) gbase[b] = atomicAdd(&gcursor[b], hist[b]);
    }
    for (int b = tid; b < NBUK; b += 256)
        for (int j = lexcl[b]; j < lexcl[b + 1]; ++j) slotbuk[j] = (unsigned short)b;
    __syncthreads();

    for (int k = tid; k < ecnt; k += 256) {
        int r = ei[e0 + k];
        int c = ei[E + e0 + k];
        int p1 = atomicAdd(&cursor[c >> 8], 1);
        stage[p1] = (unsigned int)r | ((unsigned int)(c & (BKSZ - 1)) << 17);
        int p2 = atomicAdd(&cursor[r >> 8], 1);
        stage[p2] = (unsigned int)c | ((unsigned int)(r & (BKSZ - 1)) << 17);
    }
    __syncthreads();

    for (int j = tid; j < icnt; j += 256) {
        int b = slotbuk[j];
        staged[gbase[b] + (j - lexcl[b])] = stage[j];
    }
}

// ---------------------------------------------------------------- pass B: per-bucket finalize
__global__ void binB_kernel(const int* __restrict__ bucket_base,
                            const unsigned int* __restrict__ staged,
                            int* __restrict__ csr_src, int* __restrict__ row_ptr,
                            float* __restrict__ dinv) {
    __shared__ int deghist[BKSZ];
    __shared__ int lpre[BKSZ];
    __shared__ int cur[BKSZ];
    int b = blockIdx.x;
    int node0 = b * BKSZ;
    int nn = N_NODES - node0; if (nn > BKSZ) nn = BKSZ;
    int tid = threadIdx.x;
    deghist[tid] = 0;
    __syncthreads();
    int base = bucket_base[b];
    int cnt  = bucket_base[b + 1] - base;
    for (int j = tid; j < cnt; j += 256) {
        unsigned int v = staged[base + j];
        atomicAdd(&deghist[v >> 17], 1);
    }
    __syncthreads();
    int myv = deghist[tid];
    lpre[tid] = myv;
    __syncthreads();
    for (int off = 1; off < BKSZ; off <<= 1) {
        int t = (tid >= off) ? lpre[tid - off] : 0;
        __syncthreads();
        lpre[tid] += t;
        __syncthreads();
    }
    int excl = lpre[tid] - myv;
    cur[tid] = base + excl;
    if (tid < nn) {
        row_ptr[node0 + tid] = base + excl;
        dinv[node0 + tid] = (myv > 0) ? (1.0f / sqrtf((float)myv)) : 0.0f;
    }
    if (b == NBUK - 1 && tid == 0) row_ptr[N_NODES] = base + cnt;
    __syncthreads();
    for (int j = tid; j < cnt; j += 256) {
        unsigned int v = staged[base + j];
        int pos = atomicAdd(&cur[v >> 17], 1);
        csr_src[pos] = (int)(v & 0x1FFFFu);
    }
}

// ---------------------------------------------------------------- init: vectorized float4/uint2
__global__ void init_kernel(const float* __restrict__ user_emb,
                            const float* __restrict__ item_emb,
                            const float* __restrict__ dinv,
                            unsigned int* __restrict__ embS, float* __restrict__ out) {
    int i = blockIdx.x * blockDim.x + threadIdx.x;   // over N_NODES*16 float4 units
    if (i >= N_NODES * 16) return;
    int v = i >> 4;
    float4 e = (v < NUM_USERS) ? ((const float4*)user_emb)[i]
                               : ((const float4*)item_emb)[i - NUM_USERS * 16];
    ((float4*)out)[i] = e;
    float dv = dinv[v];
    uint2 p;
    p.x = f2bf(dv * e.x) | (f2bf(dv * e.y) << 16);
    p.y = f2bf(dv * e.z) | (f2bf(dv * e.w) << 16);
    ((uint2*)embS)[i] = p;
}

// ---------------------------------------------------------------- propagation layer, one side
// ISUSER=1: update user rows (gather item rows, 3.84MB L2-resident table).
// ISUSER=0: update item rows (gather user rows).
// Wave per node; 8 groups of 8 lanes; each group gathers one source row per
// iteration as uint4 (16B/lane, 128B/row, 1KB per load instruction).
template <int LAST, int ISUSER>
__global__ void layer_kernel(const int* __restrict__ row_ptr,
                             const int* __restrict__ csr_src,
                             const float* __restrict__ dinv,
                             const unsigned int* __restrict__ embS_in,   // bf16x2 words
                             unsigned int* __restrict__ embS_out,
                             float* __restrict__ out) {
    int w    = (blockIdx.x * blockDim.x + threadIdx.x) >> 6;
    int lane = threadIdx.x & 63;
    const int NLOC = ISUSER ? NUM_USERS : NUM_ITEMS;
    if (w >= NLOC) return;
    int node = ISUSER ? w : (NUM_USERS + w);
    int g  = lane >> 3;          // source slot within iteration (0..7)
    int sl = lane & 7;           // uint4 index within row (dims 8*sl..8*sl+7)
    int start = row_ptr[node];
    int end   = row_ptr[node + 1];
    float s0 = 0.f, s1 = 0.f, s2 = 0.f, s3 = 0.f;
    float s4 = 0.f, s5 = 0.f, s6 = 0.f, s7 = 0.f;

    const uint4* tab4 = (const uint4*)embS_in;   // row = 8 uint4

    for (int j0 = start; j0 < end; j0 += 64) {
        int idx   = j0 + lane;
        int mysrc = (idx < end) ? csr_src[idx] : 0;
        int cnt   = min(64, end - j0);
        int t = 0;
        #pragma unroll 4
        for (; t + 8 <= cnt; t += 8) {           // full iterations: no guards
            int src = __shfl(mysrc, t + g);      // one ds_bpermute, per-lane index
            uint4 u = tab4[((size_t)src << 3) + sl];
            s0 += bf_lo(u.x); s1 += bf_hi(u.x);
            s2 += bf_lo(u.y); s3 += bf_hi(u.y);
            s4 += bf_lo(u.z); s5 += bf_hi(u.z);
            s6 += bf_lo(u.w); s7 += bf_hi(u.w);
        }
        if (t < cnt) {                           // predicated tail
            int tt  = t + g;
            int src = __shfl(mysrc, min(tt, cnt - 1));
            uint4 u = tab4[((size_t)src << 3) + sl];
            unsigned int m = (tt < cnt) ? 0xffffffffu : 0u;
            u.x &= m; u.y &= m; u.z &= m; u.w &= m;
            s0 += bf_lo(u.x); s1 += bf_hi(u.x);
            s2 += bf_lo(u.y); s3 += bf_hi(u.y);
            s4 += bf_lo(u.z); s5 += bf_hi(u.z);
            s6 += bf_lo(u.w); s7 += bf_hi(u.w);
        }
    }

    // reduce the 8 lane-groups (lanes differing in bits 3,4,5)
    s0 += __shfl_xor(s0, 8); s0 += __shfl_xor(s0, 16); s0 += __shfl_xor(s0, 32);
    s1 += __shfl_xor(s1, 8); s1 += __shfl_xor(s1, 16); s1 += __shfl_xor(s1, 32);
    s2 += __shfl_xor(s2, 8); s2 += __shfl_xor(s2, 16); s2 += __shfl_xor(s2, 32);
    s3 += __shfl_xor(s3, 8); s3 += __shfl_xor(s3, 16); s3 += __shfl_xor(s3, 32);
    s4 += __shfl_xor(s4, 8); s4 += __shfl_xor(s4, 16); s4 += __shfl_xor(s4, 32);
    s5 += __shfl_xor(s5, 8); s5 += __shfl_xor(s5, 16); s5 += __shfl_xor(s5, 32);
    s6 += __shfl_xor(s6, 8); s6 += __shfl_xor(s6, 16); s6 += __shfl_xor(s6, 32);
    s7 += __shfl_xor(s7, 8); s7 += __shfl_xor(s7, 16); s7 += __shfl_xor(s7, 32);

    if (lane < 8) {                              // lane sl owns dims 8*sl..8*sl+7
        float dv = dinv[node];
        float e0 = dv * s0, e1 = dv * s1, e2 = dv * s2, e3 = dv * s3;
        float e4 = dv * s4, e5 = dv * s5, e6 = dv * s6, e7 = dv * s7;
        size_t f4 = ((size_t)node << 4) + 2 * sl;     // float4 index
        float4 p0 = ((const float4*)out)[f4];
        float4 p1 = ((const float4*)out)[f4 + 1];
        if (LAST) {
            p0.x = (p0.x + e0) * 0.25f; p0.y = (p0.y + e1) * 0.25f;
            p0.z = (p0.z + e2) * 0.25f; p0.w = (p0.w + e3) * 0.25f;
            p1.x = (p1.x + e4) * 0.25f; p1.y = (p1.y + e5) * 0.25f;
            p1.z = (p1.z + e6) * 0.25f; p1.w = (p1.w + e7) * 0.25f;
            ((float4*)out)[f4]     = p0;
            ((float4*)out)[f4 + 1] = p1;
        } else {
            p0.x += e0; p0.y += e1; p0.z += e2; p0.w += e3;
            p1.x += e4; p1.y += e5; p1.z += e6; p1.w += e7;
            ((float4*)out)[f4]     = p0;
            ((float4*)out)[f4 + 1] = p1;
            uint4 q;                              // embS_out = bf16(dv*e)
            q.x = f2bf(dv * e0) | (f2bf(dv * e1) << 16);
            q.y = f2bf(dv * e2) | (f2bf(dv * e3) << 16);
            q.z = f2bf(dv * e4) | (f2bf(dv * e5) << 16);
            q.w = f2bf(dv * e6) | (f2bf(dv * e7) << 16);
            ((uint4*)embS_out)[((size_t)node << 3) + sl] = q;
        }
    }
}

// ----------------------------------------------------------------
extern "C" void kernel_launch(void* const* d_in, const int* in_sizes, int n_in,
                              void* d_out, int out_size, void* d_ws, size_t ws_size,
                              hipStream_t stream) {
    const int*   ei       = (const int*)d_in[0];
    const float* user_emb = (const float*)d_in[1];
    const float* item_emb = (const float*)d_in[2];
    float*       out      = (float*)d_out;

    char* ws = (char*)d_ws;
    size_t off = 0;
    auto alloc = [&](size_t bytes) -> void* {
        void* p = ws + off;
        off = (off + bytes + 255) & ~(size_t)255;
        return p;
    };

    int*   bucket_cnt  = (int*)  alloc((size_t)NBUK * 4);
    int*   bucket_base = (int*)  alloc(((size_t)NBUK + 1) * 4);
    int*   gcursor     = (int*)  alloc((size_t)NBUK * 4);
    int*   row_ptr     = (int*)  alloc(((size_t)N_NODES + 1) * 4);
    float* dinv        = (float*)alloc((size_t)N_NODES * 4);
    unsigned int* staged = (unsigned int*)alloc((size_t)2 * NEDGES * 4);
    int*   csr_src     = (int*)  alloc((size_t)2 * NEDGES * 4);
    unsigned int* embS0 = (unsigned int*)alloc((size_t)N_NODES * EDIM * 2);
    unsigned int* embS1 = (unsigned int*)alloc((size_t)N_NODES * EDIM * 2);

    hipMemsetAsync(bucket_cnt, 0, (size_t)NBUK * 4, stream);

    const int B = 256;
    int nbin = (NEDGES + CHUNK_E - 1) / CHUNK_E;   // 245
    histA_kernel<<<nbin, B, 0, stream>>>(ei, bucket_cnt, NEDGES);
    bscan_kernel<<<1, 64, 0, stream>>>(bucket_cnt, bucket_base, gcursor);
    binA_kernel<<<nbin, B, 0, stream>>>(ei, gcursor, staged, NEDGES);
    binB_kernel<<<NBUK, B, 0, stream>>>(bucket_base, staged, csr_src, row_ptr, dinv);

    init_kernel<<<(N_NODES * 16 + B - 1) / B, B, 0, stream>>>(user_emb, item_emb, dinv, embS0, out);

    int ugrid = NUM_USERS * 64 / B;   // 15000 blocks, one wave per user
    int igrid = NUM_ITEMS * 64 / B;   // 7500 blocks, one wave per item

    // layer 1
    layer_kernel<0, 1><<<ugrid, B, 0, stream>>>(row_ptr, csr_src, dinv, embS0, embS1, out);
    layer_kernel<0, 0><<<igrid, B, 0, stream>>>(row_ptr, csr_src, dinv, embS0, embS1, out);
    // layer 2
    layer_kernel<0, 1><<<ugrid, B, 0, stream>>>(row_ptr, csr_src, dinv, embS1, embS0, out);
    layer_kernel<0, 0><<<igrid, B, 0, stream>>>(row_ptr, csr_src, dinv, embS1, embS0, out);
    // layer 3 (fused mean)
    layer_kernel<1, 1><<<ugrid, B, 0, stream>>>(row_ptr, csr_src, dinv, embS0, nullptr, out);
    layer_kernel<1, 0><<<igrid, B, 0, stream>>>(row_ptr, csr_src, dinv, embS0, nullptr, out);
}